// Round 4
// baseline (315.196 us; speedup 1.0000x reference)
//
#include <hip/hip_runtime.h>
#include <math.h>

#define B_ 16
#define H_ 8
#define D_ 128
#define BS_ 16
#define BPS_ 128
#define T_ (BPS_ * BS_)       // 2048 tokens per sequence
#define ROW_ (H_ * D_)        // 1024 floats = 4 KiB per token row (all heads)
#define SCALE_ 0.08838834764831845f

// Kernel 1: WG = (chunk, batch), all 8 heads fused. Single streaming pass:
// per token the wave loads the full K row AND V row (contiguous 4 KiB each,
// 16B/lane) and maintains per-head online-softmax state (m, l, acc) in
// registers. No LDS / no barriers in the main loop; one-token-ahead
// register ping-pong keeps loads outstanding ~100% of wave lifetime.
template<int NS>
__global__ __launch_bounds__(256, 4) void attn_partial(
    const float* __restrict__ q,
    const float* __restrict__ knew,
    const float* __restrict__ vnew,
    const float* __restrict__ kc,
    const float* __restrict__ vc,
    const int* __restrict__ btab,
    const int* __restrict__ clen,
    float* __restrict__ ws_m,
    float* __restrict__ ws_l,
    float* __restrict__ ws_o)
{
    constexpr int CHUNK = T_ / NS;        // tokens per WG
    constexpr int TPW = CHUNK / 4;        // tokens per wave (even for NS<=64)
    constexpr int NBLK_C = CHUNK / BS_;   // cache blocks per chunk

    const int cix = blockIdx.x;
    const int b = blockIdx.y;
    const int tid = threadIdx.x;
    const int wave = tid >> 6;
    const int lane = tid & 63;
    const int hl = lane & 31;    // lane within half-wave: head dims 4*hl..4*hl+3
    const int half = lane >> 5;  // head parity within a j-slot
    const int ctx = clen[b];
    const int cs = cix * CHUNK;
    const int t0 = wave * TPW;   // wave's first token (chunk-local)

    __shared__ int   s_bt[NBLK_C];
    __shared__ float s_m[4][H_], s_l[4][H_], s_c[4][H_];
    __shared__ float s_oacc[4][H_][D_];   // 16 KiB

    if (tid < NBLK_C) s_bt[tid] = btab[b * BPS_ + cix * NBLK_C + tid];

    // q row: lane holds head (2j+half), dims 4*hl..+3, for j=0..3
    float4 q4[4];
    #pragma unroll
    for (int j = 0; j < 4; ++j)
        q4[j] = *(const float4*)(q + (size_t)b * ROW_ + j * 256 + half * 128 + 4 * hl);
    __syncthreads();

    float m[4], l[4];
    float4 acc[4];
    #pragma unroll
    for (int j = 0; j < 4; ++j) {
        m[j] = -1e30f;
        l[j] = 0.f;
        acc[j] = make_float4(0.f, 0.f, 0.f, 0.f);
    }

    auto load_tok = [&](int t, float4 (&kd)[4], float4 (&vd)[4]) {
        const int tg = cs + t0 + t;
        const int blk = s_bt[(t0 + t) >> 4];
        const float* krb = (tg == ctx - 1)
            ? (knew + (size_t)b * ROW_)
            : (kc + ((size_t)blk * BS_ + (tg & 15)) * ROW_);
        const float* vrb = (tg == ctx - 1)
            ? (vnew + (size_t)b * ROW_)
            : (vc + ((size_t)blk * BS_ + (tg & 15)) * ROW_);
        #pragma unroll
        for (int j = 0; j < 4; ++j) {
            kd[j] = *(const float4*)(krb + j * 256 + half * 128 + 4 * hl);
            vd[j] = *(const float4*)(vrb + j * 256 + half * 128 + 4 * hl);
        }
    };

    auto compute = [&](int t, float4 (&kd)[4], float4 (&vd)[4]) {
        const int tg = cs + t0 + t;
        float s[4];
        #pragma unroll
        for (int j = 0; j < 4; ++j) {
            float ss = q4[j].x * kd[j].x + q4[j].y * kd[j].y
                     + q4[j].z * kd[j].z + q4[j].w * kd[j].w;
            ss += __shfl_xor(ss, 16);
            ss += __shfl_xor(ss, 8);
            ss += __shfl_xor(ss, 4);
            ss += __shfl_xor(ss, 2);
            ss += __shfl_xor(ss, 1);
            s[j] = (tg < ctx) ? ss * SCALE_ : -INFINITY;
        }
        #pragma unroll
        for (int j = 0; j < 4; ++j) {
            const float mn = fmaxf(m[j], s[j]);
            const float al = __expf(m[j] - mn);
            const float p  = __expf(s[j] - mn);
            m[j] = mn;
            l[j] = l[j] * al + p;
            acc[j].x = acc[j].x * al + p * vd[j].x;
            acc[j].y = acc[j].y * al + p * vd[j].y;
            acc[j].z = acc[j].z * al + p * vd[j].z;
            acc[j].w = acc[j].w * al + p * vd[j].w;
        }
    };

    float4 kA[4], vA[4], kB[4], vB[4];
    load_tok(0, kA, vA);
    #pragma unroll
    for (int tt = 0; tt < TPW / 2; ++tt) {
        load_tok(2 * tt + 1, kB, vB);       // prefetch odd token
        compute(2 * tt, kA, vA);
        if (2 * tt + 2 < TPW) load_tok(2 * tt + 2, kA, vA);  // prefetch next even
        compute(2 * tt + 1, kB, vB);
    }

    // ---- wave partials -> LDS
    #pragma unroll
    for (int j = 0; j < 4; ++j) {
        *(float4*)&s_oacc[wave][2 * j + half][4 * hl] = acc[j];
        if (hl == 0) {
            s_m[wave][2 * j + half] = m[j];
            s_l[wave][2 * j + half] = l[j];
        }
    }
    __syncthreads();

    // ---- merge 4 waves with m-rescale; write chunk partial
    if (tid < H_) {
        const int h = tid;
        float M = fmaxf(fmaxf(s_m[0][h], s_m[1][h]), fmaxf(s_m[2][h], s_m[3][h]));
        float L = 0.f;
        #pragma unroll
        for (int w = 0; w < 4; ++w) {
            const float cf = __expf(s_m[w][h] - M);
            s_c[w][h] = cf;
            L += s_l[w][h] * cf;
        }
        const int idx = (b * H_ + h) * NS + cix;
        ws_m[idx] = M;
        ws_l[idx] = L;
    }
    __syncthreads();
    for (int r = tid; r < H_ * D_; r += 256) {
        const int h = r >> 7, d = r & 127;
        const float oo = s_oacc[0][h][d] * s_c[0][h] + s_oacc[1][h][d] * s_c[1][h]
                       + s_oacc[2][h][d] * s_c[2][h] + s_oacc[3][h][d] * s_c[3][h];
        ws_o[((size_t)(b * H_ + h) * NS + cix) * D_ + d] = oo;
    }
}

// Kernel 2: combine NS chunk partials per (b,h) with online-softmax rescale.
template<int NS>
__global__ __launch_bounds__(128) void attn_reduce(
    const float* __restrict__ ws_m,
    const float* __restrict__ ws_l,
    const float* __restrict__ ws_o,
    float* __restrict__ out)
{
    const int bh = blockIdx.x;    // 0..127
    const int tid = threadIdx.x;  // 0..127 = d

    __shared__ float s_co[NS];
    __shared__ float s_lg;

    if (tid < 64) {
        float m = -INFINITY;
        for (int cc = tid; cc < NS; cc += 64) m = fmaxf(m, ws_m[bh * NS + cc]);
        m = fmaxf(m, __shfl_xor(m, 32));
        m = fmaxf(m, __shfl_xor(m, 16));
        m = fmaxf(m, __shfl_xor(m, 8));
        m = fmaxf(m, __shfl_xor(m, 4));
        m = fmaxf(m, __shfl_xor(m, 2));
        m = fmaxf(m, __shfl_xor(m, 1));   // global max, all lanes
        float lw = 0.f;
        for (int cc = tid; cc < NS; cc += 64) {
            const float co = __expf(ws_m[bh * NS + cc] - m);
            s_co[cc] = co;
            lw += ws_l[bh * NS + cc] * co;
        }
        lw += __shfl_xor(lw, 32);
        lw += __shfl_xor(lw, 16);
        lw += __shfl_xor(lw, 8);
        lw += __shfl_xor(lw, 4);
        lw += __shfl_xor(lw, 2);
        lw += __shfl_xor(lw, 1);
        if (tid == 0) s_lg = lw;
    }
    __syncthreads();

    float acc = 0.f;
    #pragma unroll 8
    for (int cc = 0; cc < NS; ++cc)
        acc += s_co[cc] * ws_o[((size_t)bh * NS + cc) * D_ + tid];
    out[(size_t)bh * D_ + tid] = acc / s_lg;
}

template<int NS>
static void launch_all(const float* q, const float* knew, const float* vnew,
                       const float* kc, const float* vc,
                       const int* btab, const int* clen,
                       float* ws, float* out, hipStream_t stream)
{
    float* ws_m = ws;
    float* ws_l = ws + B_ * H_ * NS;
    float* ws_o = ws + 2 * B_ * H_ * NS;
    attn_partial<NS><<<dim3(NS, B_), 256, 0, stream>>>(q, knew, vnew, kc, vc,
                                                       btab, clen, ws_m, ws_l, ws_o);
    attn_reduce<NS><<<dim3(B_ * H_), 128, 0, stream>>>(ws_m, ws_l, ws_o, out);
}

extern "C" void kernel_launch(void* const* d_in, const int* in_sizes, int n_in,
                              void* d_out, int out_size, void* d_ws, size_t ws_size,
                              hipStream_t stream) {
    const float* q    = (const float*)d_in[0];
    const float* knew = (const float*)d_in[1];
    const float* vnew = (const float*)d_in[2];
    const float* kc   = (const float*)d_in[3];
    const float* vc   = (const float*)d_in[4];
    // d_in[5] = slot_mapping: unused — slot == position of token ctx-1 in the
    // batch's own block-table row (rows disjoint), handled by in-flight substitution.
    const int* btab = (const int*)d_in[6];
    const int* clen = (const int*)d_in[7];
    float* out = (float*)d_out;
    float* ws  = (float*)d_ws;

    // scratch need for split NS: B*H*NS*(2 + D) floats
    const size_t need64 = (size_t)B_ * H_ * 64 * (2 + D_) * sizeof(float); // ~4.1 MiB
    const size_t need32 = (size_t)B_ * H_ * 32 * (2 + D_) * sizeof(float);
    if (ws_size >= need64)      launch_all<64>(q, knew, vnew, kc, vc, btab, clen, ws, out, stream);
    else if (ws_size >= need32) launch_all<32>(q, knew, vnew, kc, vc, btab, clen, ws, out, stream);
    else                        launch_all<16>(q, knew, vnew, kc, vc, btab, clen, ws, out, stream);
}

// Round 5
// 297.724 us; speedup vs baseline: 1.0587x; 1.0587x over previous
//
#include <hip/hip_runtime.h>
#include <math.h>

#define B_ 16
#define H_ 8
#define D_ 128
#define BS_ 16
#define BPS_ 128
#define T_ (BPS_ * BS_)       // 2048 tokens per sequence
#define ROW_ (H_ * D_)        // 1024 floats = 4 KiB per token row (all heads)
#define SCALE_ 0.08838834764831845f

// async global->LDS, 16B per lane; LDS dst is wave-uniform base + lane*16.
__device__ __forceinline__ void dma16(const float* g, float* l) {
    __builtin_amdgcn_global_load_lds(
        (__attribute__((address_space(1))) void*)g,
        (__attribute__((address_space(3))) void*)l,
        16, 0, 0);
}

// Kernel 1: WG=(chunk,batch), all 8 heads fused. K/V token rows are staged
// into double-buffered LDS via global_load_lds DMA (deep queue, no VGPR
// pressure); compute reads the previous tile from LDS and keeps per-head
// online-softmax state in registers. GEMM-style 1-barrier-per-tile loop.
template<int NS>
__global__ __launch_bounds__(256, 2) void attn_partial(
    const float* __restrict__ q,
    const float* __restrict__ knew,
    const float* __restrict__ vnew,
    const float* __restrict__ kc,
    const float* __restrict__ vc,
    const int* __restrict__ btab,
    const int* __restrict__ clen,
    float* __restrict__ ws_m,
    float* __restrict__ ws_l,
    float* __restrict__ ws_o)
{
    constexpr int CHUNK = T_ / NS;       // tokens per WG
    constexpr int NTILES = CHUNK / 4;    // 4 tokens per tile (1 per wave)
    constexpr int NBLK_C = CHUNK / BS_;  // cache blocks per chunk

    const int cix = blockIdx.x;
    const int b = blockIdx.y;
    const int tid = threadIdx.x;
    const int wave = tid >> 6;
    const int lane = tid & 63;
    const int hl = lane & 31;    // lane within half-wave: dims 4*hl..4*hl+3
    const int half = lane >> 5;  // head parity within a j-slot
    const int ctx = clen[b];
    const int cs = cix * CHUNK;

    // [buf][tok][K=0/V=1][1024 floats] = 64 KiB
    __shared__ float smem[2][4][2][ROW_];
    __shared__ float s_m[4][H_], s_l[4][H_], s_c[4][H_];

    // block ids for this chunk, held in registers (const-indexed below)
    int bt[NBLK_C];
    #pragma unroll
    for (int i = 0; i < NBLK_C; ++i) bt[i] = btab[b * BPS_ + cs / BS_ + i];

    // q row: lane holds head (2j+half), dims 4*hl..+3
    float4 q4[4];
    #pragma unroll
    for (int j = 0; j < 4; ++j)
        q4[j] = *(const float4*)(q + (size_t)b * ROW_ + j * 256 + half * 128 + 4 * hl);

    float m[4], l[4];
    float4 acc[4];
    #pragma unroll
    for (int j = 0; j < 4; ++j) {
        m[j] = -1e30f;
        l[j] = 0.f;
        acc[j] = make_float4(0.f, 0.f, 0.f, 0.f);
    }

    // stage tile: wave stages token (tile*4+wave)'s K row + V row (8 KiB, 8 DMAs)
    #define STAGE(buf, tile_c, blkid)                                           \
    {                                                                           \
        const int t_ = (tile_c) * 4 + wave;                                     \
        const int tg_ = cs + t_;                                                \
        const float* krb_ = (tg_ == ctx - 1)                                    \
            ? (knew + (size_t)b * ROW_)                                         \
            : (kc + ((size_t)(blkid) * BS_ + (tg_ & 15)) * ROW_);               \
        const float* vrb_ = (tg_ == ctx - 1)                                    \
            ? (vnew + (size_t)b * ROW_)                                         \
            : (vc + ((size_t)(blkid) * BS_ + (tg_ & 15)) * ROW_);               \
        _Pragma("unroll")                                                       \
        for (int qq = 0; qq < 4; ++qq) {                                        \
            dma16(krb_ + qq * 256 + lane * 4, &smem[buf][wave][0][qq * 256]);   \
            dma16(vrb_ + qq * 256 + lane * 4, &smem[buf][wave][1][qq * 256]);   \
        }                                                                       \
    }

    STAGE(0, 0, bt[0]);
    __syncthreads();   // drains tile-0 DMAs

    #pragma unroll
    for (int tile = 0; tile < NTILES; ++tile) {
        if (tile + 1 < NTILES) STAGE((tile + 1) & 1, tile + 1, bt[(tile + 1) >> 2]);

        // compute this wave's token of tile from LDS
        {
            const int t = tile * 4 + wave;
            const int tg = cs + t;
            float4 kd[4], vd[4];
            #pragma unroll
            for (int j = 0; j < 4; ++j) {
                kd[j] = *(const float4*)&smem[tile & 1][wave][0][j * 256 + half * 128 + 4 * hl];
                vd[j] = *(const float4*)&smem[tile & 1][wave][1][j * 256 + half * 128 + 4 * hl];
            }
            float s[4];
            #pragma unroll
            for (int j = 0; j < 4; ++j) {
                float ss = q4[j].x * kd[j].x + q4[j].y * kd[j].y
                         + q4[j].z * kd[j].z + q4[j].w * kd[j].w;
                ss += __shfl_xor(ss, 16);
                ss += __shfl_xor(ss, 8);
                ss += __shfl_xor(ss, 4);
                ss += __shfl_xor(ss, 2);
                ss += __shfl_xor(ss, 1);
                s[j] = (tg < ctx) ? ss * SCALE_ : -INFINITY;
            }
            #pragma unroll
            for (int j = 0; j < 4; ++j) {
                const float mn = fmaxf(m[j], s[j]);
                const float al = __expf(m[j] - mn);
                const float p  = __expf(s[j] - mn);
                m[j] = mn;
                l[j] = l[j] * al + p;
                acc[j].x = acc[j].x * al + p * vd[j].x;
                acc[j].y = acc[j].y * al + p * vd[j].y;
                acc[j].z = acc[j].z * al + p * vd[j].z;
                acc[j].w = acc[j].w * al + p * vd[j].w;
            }
        }
        __syncthreads();   // drains next tile's DMAs + protects buffer reuse
    }
    #undef STAGE

    // ---- wave partials -> LDS (staging buffers are dead; overlay merge array)
    float (*s_oacc)[H_][D_] = reinterpret_cast<float(*)[H_][D_]>(&smem[0][0][0][0]);
    #pragma unroll
    for (int j = 0; j < 4; ++j) {
        *(float4*)&s_oacc[wave][2 * j + half][4 * hl] = acc[j];
        if (hl == 0) {
            s_m[wave][2 * j + half] = m[j];
            s_l[wave][2 * j + half] = l[j];
        }
    }
    __syncthreads();

    // ---- merge 4 waves with m-rescale; write chunk partial
    if (tid < H_) {
        const int h = tid;
        float M = fmaxf(fmaxf(s_m[0][h], s_m[1][h]), fmaxf(s_m[2][h], s_m[3][h]));
        float L = 0.f;
        #pragma unroll
        for (int w = 0; w < 4; ++w) {
            const float cf = __expf(s_m[w][h] - M);
            s_c[w][h] = cf;
            L += s_l[w][h] * cf;
        }
        const int idx = (b * H_ + h) * NS + cix;
        ws_m[idx] = M;
        ws_l[idx] = L;
    }
    __syncthreads();
    for (int r = tid; r < H_ * D_; r += 256) {
        const int h = r >> 7, d = r & 127;
        const float oo = s_oacc[0][h][d] * s_c[0][h] + s_oacc[1][h][d] * s_c[1][h]
                       + s_oacc[2][h][d] * s_c[2][h] + s_oacc[3][h][d] * s_c[3][h];
        ws_o[((size_t)(b * H_ + h) * NS + cix) * D_ + d] = oo;
    }
}

// Kernel 2: combine NS chunk partials per (b,h) with online-softmax rescale.
template<int NS>
__global__ __launch_bounds__(128) void attn_reduce(
    const float* __restrict__ ws_m,
    const float* __restrict__ ws_l,
    const float* __restrict__ ws_o,
    float* __restrict__ out)
{
    const int bh = blockIdx.x;    // 0..127
    const int tid = threadIdx.x;  // 0..127 = d

    __shared__ float s_co[NS];
    __shared__ float s_lg;

    if (tid < 64) {
        float m = -INFINITY;
        for (int cc = tid; cc < NS; cc += 64) m = fmaxf(m, ws_m[bh * NS + cc]);
        m = fmaxf(m, __shfl_xor(m, 32));
        m = fmaxf(m, __shfl_xor(m, 16));
        m = fmaxf(m, __shfl_xor(m, 8));
        m = fmaxf(m, __shfl_xor(m, 4));
        m = fmaxf(m, __shfl_xor(m, 2));
        m = fmaxf(m, __shfl_xor(m, 1));   // global max, all lanes
        float lw = 0.f;
        for (int cc = tid; cc < NS; cc += 64) {
            const float co = __expf(ws_m[bh * NS + cc] - m);
            s_co[cc] = co;
            lw += ws_l[bh * NS + cc] * co;
        }
        lw += __shfl_xor(lw, 32);
        lw += __shfl_xor(lw, 16);
        lw += __shfl_xor(lw, 8);
        lw += __shfl_xor(lw, 4);
        lw += __shfl_xor(lw, 2);
        lw += __shfl_xor(lw, 1);
        if (tid == 0) s_lg = lw;
    }
    __syncthreads();

    float acc = 0.f;
    #pragma unroll 8
    for (int cc = 0; cc < NS; ++cc)
        acc += s_co[cc] * ws_o[((size_t)bh * NS + cc) * D_ + tid];
    out[(size_t)bh * D_ + tid] = acc / s_lg;
}

template<int NS>
static void launch_all(const float* q, const float* knew, const float* vnew,
                       const float* kc, const float* vc,
                       const int* btab, const int* clen,
                       float* ws, float* out, hipStream_t stream)
{
    float* ws_m = ws;
    float* ws_l = ws + B_ * H_ * NS;
    float* ws_o = ws + 2 * B_ * H_ * NS;
    attn_partial<NS><<<dim3(NS, B_), 256, 0, stream>>>(q, knew, vnew, kc, vc,
                                                       btab, clen, ws_m, ws_l, ws_o);
    attn_reduce<NS><<<dim3(B_ * H_), 128, 0, stream>>>(ws_m, ws_l, ws_o, out);
}

extern "C" void kernel_launch(void* const* d_in, const int* in_sizes, int n_in,
                              void* d_out, int out_size, void* d_ws, size_t ws_size,
                              hipStream_t stream) {
    const float* q    = (const float*)d_in[0];
    const float* knew = (const float*)d_in[1];
    const float* vnew = (const float*)d_in[2];
    const float* kc   = (const float*)d_in[3];
    const float* vc   = (const float*)d_in[4];
    // d_in[5] = slot_mapping: unused — slot == position of token ctx-1 in the
    // batch's own block-table row (rows disjoint), handled by in-flight substitution.
    const int* btab = (const int*)d_in[6];
    const int* clen = (const int*)d_in[7];
    float* out = (float*)d_out;
    float* ws  = (float*)d_ws;

    // scratch need for split NS: B*H*NS*(2 + D) floats
    const size_t need64 = (size_t)B_ * H_ * 64 * (2 + D_) * sizeof(float); // ~4.2 MiB
    const size_t need32 = (size_t)B_ * H_ * 32 * (2 + D_) * sizeof(float);
    if (ws_size >= need64)      launch_all<64>(q, knew, vnew, kc, vc, btab, clen, ws, out, stream);
    else if (ws_size >= need32) launch_all<32>(q, knew, vnew, kc, vc, btab, clen, ws, out, stream);
    else                        launch_all<16>(q, knew, vnew, kc, vc, btab, clen, ws, out, stream);
}